// Round 4
// baseline (2124.943 us; speedup 1.0000x reference)
//
#include <hip/hip_runtime.h>
#include <hip/hip_bf16.h>

#define BSZ    256
#define SEQT   2048
#define NVOCAB 10
#define DEMB   32
#define G4     256

typedef unsigned short u16;
typedef unsigned int   u32;
typedef float    v2f __attribute__((ext_vector_type(2)));
typedef float    v4f __attribute__((ext_vector_type(4)));
typedef u32      v4u __attribute__((ext_vector_type(4)));
typedef _Float16 v2h __attribute__((ext_vector_type(2)));

// ws layout (float slots; some hold u32/f16-pair bits)
#define FLAG_OFF 0
#define XZG_OFF  1                    // [4 gates][10 vocab][64 unit] f32 = 2560
#define WHI_OFF  (XZG_OFF + 2560)    // [64 j][32 kpair][2] f32 = 4096
#define WHF_OFF  (WHI_OFF + 4096)
#define WHG_OFF  (WHF_OFF + 4096)
#define WHO_OFF  (WHG_OFF + 4096)
#define W1P_OFF  (WHO_OFF + 4096)    // u32: [64 o][64 kpair] f16x2 = 4096
#define W2P_OFF  (W1P_OFF + 4096)    // u32: [32 o][32 kpair] = 1024
#define W3_OFF   (W2P_OFF + 1024)    // f32 [32][10] = 320
#define B1_OFF   (W3_OFF + 320)
#define B2_OFF   (B1_OFF + 64)
#define B3_OFF   (B2_OFF + 32)

__device__ __forceinline__ float bf2f(u16 x) {
    union { u32 u; float f; } v; v.u = ((u32)x) << 16; return v.f;
}
__device__ __forceinline__ u16 f2bf(float f) {
    union { float f; u32 u; } v; v.f = f;
    u32 r = v.u + 0x7fff + ((v.u >> 16) & 1);
    return (u16)(r >> 16);
}
__device__ __forceinline__ float ldw(const void* p, int i, bool isbf) {
    return isbf ? bf2f(((const u16*)p)[i]) : ((const float*)p)[i];
}
__device__ __forceinline__ float frcp(float x) { return __builtin_amdgcn_rcpf(x); }
__device__ __forceinline__ float sigf(float z) { return frcp(1.f + __expf(-z)); }  // inf-safe
__device__ __forceinline__ u16 f2h(float x) {
    union { _Float16 h; u16 u; } v; v.h = (_Float16)x; return v.u;
}
__device__ __forceinline__ u32 packh2(float lo, float hi) {
    return (u32)f2h(lo) | ((u32)f2h(hi) << 16);
}
// packed fp32 FMA: acc.xy += a.xy * b.xy (exact fp32, 2 MACs / instr)
__device__ __forceinline__ void pkfma(v2f& acc, v2f a, v2f b) {
    asm("v_pk_fma_f32 %0, %1, %2, %0" : "+v"(acc) : "v"(a), "v"(b));
}
__device__ __forceinline__ float fdot2f(u32 a, u32 b, float c) {
    union { u32 u; v2h h; } ua, ub; ua.u = a; ub.u = b;
    return __builtin_amdgcn_fdot2(ua.h, ub.h, c, false);
}

// One-time prep: dtype detect, xz table (E@Wx+b: only 10 rows), per-lane Wh pair
// tables (fp32), f16-packed MLP weights.
__global__ void init_kernel(const void* __restrict__ E,  const void* __restrict__ Wx,
                            const void* __restrict__ Wh, const void* __restrict__ bg,
                            const void* __restrict__ W1, const void* __restrict__ b1,
                            const void* __restrict__ W2, const void* __restrict__ b2,
                            const void* __restrict__ W3, const void* __restrict__ b3,
                            float* __restrict__ ws) {
    __shared__ int s_isbf;
    const int tid = threadIdx.x;  // 256 threads, 1 block
    if (tid == 0) s_isbf = 1;
    __syncthreads();
    {   // bf16 data decodes small; fp32 low-halves decode wild exponents
        const u16* Eu = (const u16*)E;
        for (int i = tid; i < NVOCAB * DEMB; i += 256) {
            float v = bf2f(Eu[i]);
            if (!(fabsf(v) < 16.0f)) s_isbf = 0;
        }
    }
    __syncthreads();
    const bool isbf = (s_isbf != 0);
    if (tid == 0) ws[FLAG_OFF] = isbf ? 1.0f : 0.0f;
    u32* wsu = (u32*)ws;

    {   // xz[v][g] = b[g] + sum_d E[v][d]*Wx[d][g]  -> layout [gate][v][j]
        const int g = tid, gt = g >> 6, j = g & 63;
        for (int v = 0; v < NVOCAB; v++) {
            float acc = ldw(bg, g, isbf);
            #pragma unroll
            for (int d = 0; d < DEMB; d++)
                acc += ldw(E, v * DEMB + d, isbf) * ldw(Wx, d * G4 + g, isbf);
            ws[XZG_OFF + gt * 640 + v * 64 + j] = acc;
        }
    }
    // Wh pair tables: WHx[(j*32+kk)*2 + e] = Wh[2kk+e][col(j)]
    for (int i = tid; i < 2048; i += 256) {
        int j = i >> 5, kk = i & 31;
        ws[WHI_OFF + i * 2]     = ldw(Wh, (2 * kk) * G4 + j, isbf);
        ws[WHI_OFF + i * 2 + 1] = ldw(Wh, (2 * kk + 1) * G4 + j, isbf);
        ws[WHF_OFF + i * 2]     = ldw(Wh, (2 * kk) * G4 + 64 + j, isbf);
        ws[WHF_OFF + i * 2 + 1] = ldw(Wh, (2 * kk + 1) * G4 + 64 + j, isbf);
        ws[WHG_OFF + i * 2]     = ldw(Wh, (2 * kk) * G4 + 128 + j, isbf);
        ws[WHG_OFF + i * 2 + 1] = ldw(Wh, (2 * kk + 1) * G4 + 128 + j, isbf);
        ws[WHO_OFF + i * 2]     = ldw(Wh, (2 * kk) * G4 + 192 + j, isbf);
        ws[WHO_OFF + i * 2 + 1] = ldw(Wh, (2 * kk + 1) * G4 + 192 + j, isbf);
    }
    for (int i = tid; i < 4096; i += 256) {   // W1 [128][64] -> [o][kpair] f16x2
        int o = i >> 6, kk = i & 63;
        wsu[W1P_OFF + i] = packh2(ldw(W1, (2 * kk) * 64 + o, isbf),
                                  ldw(W1, (2 * kk + 1) * 64 + o, isbf));
    }
    for (int i = tid; i < 1024; i += 256) {   // W2 [64][32] -> [o][kpair]
        int o = i >> 5, kk = i & 31;
        wsu[W2P_OFF + i] = packh2(ldw(W2, (2 * kk) * 32 + o, isbf),
                                  ldw(W2, (2 * kk + 1) * 32 + o, isbf));
    }
    for (int i = tid; i < 320; i += 256) ws[W3_OFF + i] = ldw(W3, i, isbf);
    if (tid < 64) ws[B1_OFF + tid] = ldw(b1, tid, isbf);
    if (tid < 32) ws[B2_OFF + tid] = ldw(b2, tid, isbf);
    if (tid < NVOCAB) ws[B3_OFF + tid] = ldw(b3, tid, isbf);
}

// One block (256 thr, 4 waves) per batch element:
//   waves 0,1: one LSTM chain each, Wh register-resident, barrier-free steps.
//   waves 2,3: MLP head on the previous 32-token window + index prefetch.
// Block-wide sync only once per 32-step window (65 total).
__global__ __launch_bounds__(256, 1) void lstm_fused(
    const int* __restrict__ num1, const int* __restrict__ num2,
    const float* __restrict__ ws, void* __restrict__ outv)
{
    __shared__ float xzg[2560];                         // 10240 B
    __shared__ __align__(16) float hring[2][128];       //  1024 B (fp32 recurrence)
    __shared__ __align__(16) u16 hwinh[2][32][128];     // 16384 B (f16 MLP window)
    __shared__ __align__(16) u32 W1p[64 * 68];          // 17408 B
    __shared__ __align__(16) u32 W2p[32 * 36];          //  4608 B
    __shared__ float W3s[320];                          //  1280 B
    __shared__ __align__(16) u16 w1h[32 * 72];          //  4608 B
    __shared__ float w2buf[32 * 36];                    //  4608 B
    __shared__ int idxs[2][2][32];                      //   512 B  -> ~59.6 KB

    const int tid = threadIdx.x, bb = blockIdx.x;
    const int wv = tid >> 6, l = tid & 63;
    const u32* wsu = (const u32*)ws;
    const bool outbf = (ws[FLAG_OFF] != 0.0f);

    for (int i = tid; i < 2560; i += 256) xzg[i] = ws[XZG_OFF + i];
    for (int i = tid; i < 4096; i += 256) { int o = i >> 6, kk = i & 63; W1p[o * 68 + kk] = wsu[W1P_OFF + i]; }
    for (int i = tid; i < 1024; i += 256) { int o = i >> 5, kk = i & 31; W2p[o * 36 + kk] = wsu[W2P_OFF + i]; }
    for (int i = tid; i < 320; i += 256) W3s[i] = ws[W3_OFF + i];
    if (tid < 128) hring[1][tid] = 0.f;                 // h_{-1} = 0
    if (tid < 64) { int c0 = tid >> 5, tt = tid & 31;
                    idxs[0][c0][tt] = (c0 == 0 ? num1 : num2)[bb * SEQT + tt]; }

    if (wv < 2) {
        // ---------------- recurrence wave: chain wv, lane l = unit ----------------
        v2f whi[32], whf[32], whg[32], who[32];         // 256 VGPRs of Wh
        #pragma unroll
        for (int kk = 0; kk < 32; kk++) {
            whi[kk] = *(const v2f*)&ws[WHI_OFF + (l * 32 + kk) * 2];
            whf[kk] = *(const v2f*)&ws[WHF_OFF + (l * 32 + kk) * 2];
            whg[kk] = *(const v2f*)&ws[WHG_OFF + (l * 32 + kk) * 2];
            who[kk] = *(const v2f*)&ws[WHO_OFF + (l * 32 + kk) * 2];
        }
        float c = 0.f;
        __syncthreads();
        for (int win = 0; win <= 64; win++) {
            if (win < 64) {
                const int wb = win & 1;
                #pragma unroll 1
                for (int tt = 0; tt < 32; tt++) {
                    const int idx = idxs[wb][wv][tt];
                    const int xb = idx * 64 + l;
                    float xzi = xzg[xb], xzf = xzg[xb + 640];
                    float xzG = xzg[xb + 1280], xzo = xzg[xb + 1920];
                    const v4f* hp = (const v4f*)&hring[1 - (tt & 1)][wv * 64];
                    v2f ai = {0.f, 0.f}, af = {0.f, 0.f}, ag = {0.f, 0.f}, ao = {0.f, 0.f};
                    #pragma unroll
                    for (int kk = 0; kk < 16; kk++) {
                        v4f h4 = hp[kk];
                        v2f hlo = h4.xy, hhi = h4.zw;
                        pkfma(ai, whi[2 * kk], hlo); pkfma(af, whf[2 * kk], hlo);
                        pkfma(ag, whg[2 * kk], hlo); pkfma(ao, who[2 * kk], hlo);
                        pkfma(ai, whi[2 * kk + 1], hhi); pkfma(af, whf[2 * kk + 1], hhi);
                        pkfma(ag, whg[2 * kk + 1], hhi); pkfma(ao, who[2 * kk + 1], hhi);
                    }
                    float zi = ai.x + ai.y + xzi, zf = af.x + af.y + xzf;
                    float zg = ag.x + ag.y + xzG, zo = ao.x + ao.y + xzo;
                    float gi = sigf(zi), gf = sigf(zf);
                    float gG = 2.f * sigf(2.f * zg) - 1.f, go = sigf(zo);
                    c = gf * c + gi * gG;
                    float th = 1.f - 2.f * frcp(__expf(2.f * c) + 1.f);  // inf-safe tanh
                    float h = go * th;
                    hring[tt & 1][wv * 64 + l] = h;            // next step (fp32)
                    hwinh[wb][tt][wv * 64 + l] = f2h(h);       // MLP window (f16)
                }
            }
            __syncthreads();
        }
    } else {
        // ---------------- MLP wave: tokens [tb, tb+16) of previous window ----------
        const int tb = (wv - 2) * 16;
        const float b1o = ws[B1_OFF + l];
        const int th = l >> 5, o2 = l & 31;
        const float b2o = ws[B2_OFF + o2];
        const int tloc = l / 10, o3 = l - tloc * 10;
        const float b3o = (l < 40) ? ws[B3_OFF + o3] : 0.f;
        const int* nums = (wv == 2 ? num1 : num2) + bb * SEQT;
        u16* outb = (u16*)outv; float* outf = (float*)outv;
        __syncthreads();
        for (int win = 0; win <= 64; win++) {
            if (win < 63 && l < 32)
                idxs[(win + 1) & 1][wv - 2][l] = nums[(win + 1) * 32 + l];
            if (win >= 1) {
                const int pw = win - 1, pwb = pw & 1;
                // L1: z[tk][o] = relu(b1 + sum_k hwin[tk][k]*W1[k][o]), o = l
                float acc[16];
                #pragma unroll
                for (int i = 0; i < 16; i++) acc[i] = b1o;
                for (int kc = 0; kc < 16; kc++) {
                    v4u wq = *(const v4u*)&W1p[l * 68 + 4 * kc];
                    #pragma unroll
                    for (int i = 0; i < 16; i++) {
                        v4u hq = *(const v4u*)&hwinh[pwb][tb + i][8 * kc];
                        float a = acc[i];
                        a = fdot2f(wq.x, hq.x, a); a = fdot2f(wq.y, hq.y, a);
                        a = fdot2f(wq.z, hq.z, a); a = fdot2f(wq.w, hq.w, a);
                        acc[i] = a;
                    }
                }
                #pragma unroll
                for (int i = 0; i < 16; i++)
                    w1h[(tb + i) * 72 + l] = f2h(fmaxf(acc[i], 0.f));
                // L2: own-wave rows, same-wave LDS ordering (no barrier)
                float a2[8];
                #pragma unroll
                for (int i = 0; i < 8; i++) a2[i] = b2o;
                for (int kc = 0; kc < 8; kc++) {
                    v4u wq = *(const v4u*)&W2p[o2 * 36 + 4 * kc];
                    #pragma unroll
                    for (int i = 0; i < 8; i++) {
                        v4u hq = *(const v4u*)&w1h[(tb + th * 8 + i) * 72 + 8 * kc];
                        float a = a2[i];
                        a = fdot2f(wq.x, hq.x, a); a = fdot2f(wq.y, hq.y, a);
                        a = fdot2f(wq.z, hq.z, a); a = fdot2f(wq.w, hq.w, a);
                        a2[i] = a;
                    }
                }
                #pragma unroll
                for (int i = 0; i < 8; i++)
                    w2buf[(tb + th * 8 + i) * 36 + o2] = fmaxf(a2[i], 0.f);
                // L3: [16 tok][32] @ [32][10]
                if (l < 40) {
                    #pragma unroll
                    for (int i = 0; i < 4; i++) {
                        const int tk = tb + tloc * 4 + i;
                        float a = b3o;
                        #pragma unroll 8
                        for (int k = 0; k < 32; k++)
                            a += W3s[k * 10 + o3] * w2buf[tk * 36 + k];
                        const size_t oi = (size_t)(bb * SEQT + pw * 32 + tk) * NVOCAB + o3;
                        if (outbf) outb[oi] = f2bf(a); else outf[oi] = a;
                    }
                }
            }
            __syncthreads();
        }
    }
}

extern "C" void kernel_launch(void* const* d_in, const int* in_sizes, int n_in,
                              void* d_out, int out_size, void* d_ws, size_t ws_size,
                              hipStream_t stream) {
    const int* num1 = (const int*)d_in[0];
    const int* num2 = (const int*)d_in[1];
    float* ws = (float*)d_ws;

    hipLaunchKernelGGL(init_kernel, dim3(1), dim3(256), 0, stream,
                       d_in[2], d_in[3], d_in[4], d_in[5], d_in[6], d_in[7],
                       d_in[8], d_in[9], d_in[10], d_in[11], ws);
    hipLaunchKernelGGL(lstm_fused, dim3(BSZ), dim3(256), 0, stream,
                       num1, num2, ws, d_out);
}

// Round 5
// 1016.800 us; speedup vs baseline: 2.0898x; 2.0898x over previous
//
#include <hip/hip_runtime.h>
#include <hip/hip_bf16.h>

#define BSZ    256
#define SEQT   2048
#define NVOCAB 10
#define DEMB   32
#define G4     256

typedef unsigned short u16;
typedef unsigned int   u32;
typedef float    v4f __attribute__((ext_vector_type(4)));
typedef u32      v4u __attribute__((ext_vector_type(4)));
typedef _Float16 v2h __attribute__((ext_vector_type(2)));

// ws layout (float slots; some regions hold u32 f16-pair bits)
#define FLAG_OFF 0
#define XZ4_OFF  4                      // [10 v][64 j][4 g] f32 = 2560 (16B aligned)
#define WHP_OFF  (XZ4_OFF + 2560)      // u32 [64 l][4 g][32 kpair] = 8192
#define W1P_OFF  (WHP_OFF + 8192)      // u32 [64 o][64 kpair] = 4096
#define W2P_OFF  (W1P_OFF + 4096)      // u32 [32 o][32 kpair] = 1024
#define W3_OFF   (W2P_OFF + 1024)      // f32 [32][10] = 320
#define B1_OFF   (W3_OFF + 320)
#define B2_OFF   (B1_OFF + 64)
#define B3_OFF   (B2_OFF + 32)

__device__ __forceinline__ float bf2f(u16 x) {
    union { u32 u; float f; } v; v.u = ((u32)x) << 16; return v.f;
}
__device__ __forceinline__ u16 f2bf(float f) {
    union { float f; u32 u; } v; v.f = f;
    u32 r = v.u + 0x7fff + ((v.u >> 16) & 1);
    return (u16)(r >> 16);
}
__device__ __forceinline__ float ldw(const void* p, int i, bool isbf) {
    return isbf ? bf2f(((const u16*)p)[i]) : ((const float*)p)[i];
}
__device__ __forceinline__ float frcp(float x) { return __builtin_amdgcn_rcpf(x); }
__device__ __forceinline__ float sigf(float z) { return frcp(1.f + __expf(-z)); }  // inf-safe
__device__ __forceinline__ u16 f2h(float x) {
    union { _Float16 h; u16 u; } v; v.h = (_Float16)x; return v.u;
}
__device__ __forceinline__ u32 packh2(float lo, float hi) {
    return (u32)f2h(lo) | ((u32)f2h(hi) << 16);
}
__device__ __forceinline__ float fdot2f(u32 a, u32 b, float c) {
    union { u32 u; v2h h; } ua, ub; ua.u = a; ub.u = b;
    return __builtin_amdgcn_fdot2(ua.h, ub.h, c, false);
}
// 4 f16-pair dots: acc += w.h (8 MACs), f32 accumulation
__device__ __forceinline__ void dot4(float& acc, v4u w, v4u h) {
    acc = fdot2f(w.x, h.x, acc); acc = fdot2f(w.y, h.y, acc);
    acc = fdot2f(w.z, h.z, acc); acc = fdot2f(w.w, h.w, acc);
}

// One-time prep: dtype detect, xz float4 table (E@Wx+b: 10 rows), per-lane
// f16-packed Wh table, f16-packed MLP weights.
__global__ void init_kernel(const void* __restrict__ E,  const void* __restrict__ Wx,
                            const void* __restrict__ Wh, const void* __restrict__ bg,
                            const void* __restrict__ W1, const void* __restrict__ b1,
                            const void* __restrict__ W2, const void* __restrict__ b2,
                            const void* __restrict__ W3, const void* __restrict__ b3,
                            float* __restrict__ ws) {
    __shared__ int s_isbf;
    const int tid = threadIdx.x;  // 256 threads, 1 block
    if (tid == 0) s_isbf = 1;
    __syncthreads();
    {   // bf16 data decodes small; fp32 low-halves decode wild exponents
        const u16* Eu = (const u16*)E;
        for (int i = tid; i < NVOCAB * DEMB; i += 256) {
            float v = bf2f(Eu[i]);
            if (!(fabsf(v) < 16.0f)) s_isbf = 0;
        }
    }
    __syncthreads();
    const bool isbf = (s_isbf != 0);
    if (tid == 0) ws[FLAG_OFF] = isbf ? 1.0f : 0.0f;
    u32* wsu = (u32*)ws;

    {   // xz[v][j][g] = b[g*64+j] + sum_d E[v][d]*Wx[d][g*64+j]  (float4 over g)
        const int g = tid >> 6, j = tid & 63, col = g * 64 + j;
        for (int v = 0; v < NVOCAB; v++) {
            float acc = ldw(bg, col, isbf);
            #pragma unroll
            for (int d = 0; d < DEMB; d++)
                acc += ldw(E, v * DEMB + d, isbf) * ldw(Wx, d * G4 + col, isbf);
            ws[XZ4_OFF + (v * 64 + j) * 4 + g] = acc;
        }
    }
    // Wh per-lane table: u32[l*128 + g*32 + kk] = pack(Wh[2kk][g*64+l], Wh[2kk+1][g*64+l])
    for (int i = tid; i < 8192; i += 256) {
        int l = i >> 7, rem = i & 127, g = rem >> 5, kk = rem & 31;
        int col = g * 64 + l;
        wsu[WHP_OFF + i] = packh2(ldw(Wh, (2 * kk) * G4 + col, isbf),
                                  ldw(Wh, (2 * kk + 1) * G4 + col, isbf));
    }
    for (int i = tid; i < 4096; i += 256) {   // W1 [128][64] -> [o][kpair] f16x2
        int o = i >> 6, kk = i & 63;
        wsu[W1P_OFF + i] = packh2(ldw(W1, (2 * kk) * 64 + o, isbf),
                                  ldw(W1, (2 * kk + 1) * 64 + o, isbf));
    }
    for (int i = tid; i < 1024; i += 256) {   // W2 [64][32] -> [o][kpair]
        int o = i >> 5, kk = i & 31;
        wsu[W2P_OFF + i] = packh2(ldw(W2, (2 * kk) * 32 + o, isbf),
                                  ldw(W2, (2 * kk + 1) * 32 + o, isbf));
    }
    for (int i = tid; i < 320; i += 256) ws[W3_OFF + i] = ldw(W3, i, isbf);
    if (tid < 64) ws[B1_OFF + tid] = ldw(b1, tid, isbf);
    if (tid < 32) ws[B2_OFF + tid] = ldw(b2, tid, isbf);
    if (tid < NVOCAB) ws[B3_OFF + tid] = ldw(b3, tid, isbf);
}

// One block (256 thr, 4 waves) per batch element:
//   waves 0,1: one LSTM chain each; Wh register-resident as f16 pairs (128 VGPRs,
//              no spill), v_dot2_f32_f16 matvec, barrier-free steps.
//   waves 2,3: MLP head on the previous 32-token window + index prefetch.
// Block-wide sync once per 32-step window (65 total).
__global__ __launch_bounds__(256, 1) void lstm_fused(
    const int* __restrict__ num1, const int* __restrict__ num2,
    const float* __restrict__ ws, void* __restrict__ outv)
{
    __shared__ __align__(16) float xz4s[2560];          // 10240 B
    __shared__ __align__(16) u16 hwinh[2][32][128];     // 16384 B (f16 h, dbuf window)
    __shared__ __align__(16) u32 W1p[64 * 68];          // 17408 B
    __shared__ __align__(16) u32 W2p[32 * 36];          //  4608 B
    __shared__ float W3s[320];                          //  1280 B
    __shared__ __align__(16) u16 w1h[32 * 72];          //  4608 B
    __shared__ float w2buf[32 * 36];                    //  4608 B
    __shared__ int idxs[2][2][32];                      //   512 B  -> ~59.6 KB

    const int tid = threadIdx.x, bb = blockIdx.x;
    const int wv = tid >> 6, l = tid & 63;
    const u32* wsu = (const u32*)ws;
    const bool outbf = (ws[FLAG_OFF] != 0.0f);

    for (int i = tid; i < 2560; i += 256) xz4s[i] = ws[XZ4_OFF + i];
    for (int i = tid; i < 4096; i += 256) { int o = i >> 6, kk = i & 63; W1p[o * 68 + kk] = wsu[W1P_OFF + i]; }
    for (int i = tid; i < 1024; i += 256) { int o = i >> 5, kk = i & 31; W2p[o * 36 + kk] = wsu[W2P_OFF + i]; }
    for (int i = tid; i < 320; i += 256) W3s[i] = ws[W3_OFF + i];
    if (tid < 128) hwinh[1][31][tid] = 0;               // h_{-1} = 0 (f16 zero)
    if (tid < 64) { int c0 = tid >> 5, tt = tid & 31;
                    idxs[0][c0][tt] = (c0 == 0 ? num1 : num2)[bb * SEQT + tt]; }

    if (wv < 2) {
        // -------- recurrence wave: chain wv, lane l = unit --------
        v4u whq[32];                                    // 128 VGPRs of f16-pair Wh
        {
            const v4u* whsrc = (const v4u*)(wsu + WHP_OFF) + (size_t)l * 32;
            #pragma unroll
            for (int i = 0; i < 32; i++) whq[i] = whsrc[i];
        }
        float c = 0.f;
        __syncthreads();
        for (int win = 0; win <= 64; win++) {
            if (win < 64) {
                const int wb = win & 1;
                #pragma unroll 1
                for (int tt = 0; tt < 32; tt++) {
                    const int idx  = idxs[wb][wv][tt];
                    const int rbuf = (tt == 0) ? 1 - wb : wb;
                    const int rrow = (tt + 31) & 31;
                    const v4u* hp = (const v4u*)&hwinh[rbuf][rrow][wv * 64];
                    v4u hh[8];
                    #pragma unroll
                    for (int q = 0; q < 8; q++) hh[q] = hp[q];
                    v4f xzv = *(const v4f*)&xz4s[(idx * 64 + l) * 4];
                    float ai0 = 0.f, af0 = 0.f, ag0 = 0.f, ao0 = 0.f;
                    float ai1 = 0.f, af1 = 0.f, ag1 = 0.f, ao1 = 0.f;
                    #pragma unroll
                    for (int q = 0; q < 4; q++) {
                        dot4(ai0, whq[q],      hh[q]);
                        dot4(af0, whq[8 + q],  hh[q]);
                        dot4(ag0, whq[16 + q], hh[q]);
                        dot4(ao0, whq[24 + q], hh[q]);
                    }
                    #pragma unroll
                    for (int q = 4; q < 8; q++) {
                        dot4(ai1, whq[q],      hh[q]);
                        dot4(af1, whq[8 + q],  hh[q]);
                        dot4(ag1, whq[16 + q], hh[q]);
                        dot4(ao1, whq[24 + q], hh[q]);
                    }
                    float zi = ai0 + ai1 + xzv.x, zf = af0 + af1 + xzv.y;
                    float zg = ag0 + ag1 + xzv.z, zo = ao0 + ao1 + xzv.w;
                    float gi = sigf(zi), gf = sigf(zf);
                    float gG = 2.f * sigf(2.f * zg) - 1.f, go = sigf(zo);
                    c = gf * c + gi * gG;
                    float th = 1.f - 2.f * frcp(__expf(2.f * c) + 1.f);  // inf-safe tanh
                    hwinh[wb][tt][wv * 64 + l] = f2h(go * th);
                    // same-wave DS ordering: next step's read of this row needs no barrier
                }
            }
            __syncthreads();
        }
    } else {
        // -------- MLP wave: tokens [tb, tb+16) of previous window --------
        const int tb = (wv - 2) * 16;
        const float b1o = ws[B1_OFF + l];
        const int th = l >> 5, o2 = l & 31;
        const float b2o = ws[B2_OFF + o2];
        const int tloc = l / 10, o3 = l - tloc * 10;
        const float b3o = (l < 40) ? ws[B3_OFF + o3] : 0.f;
        const int* nums = (wv == 2 ? num1 : num2) + bb * SEQT;
        u16* outb = (u16*)outv; float* outf = (float*)outv;
        __syncthreads();
        for (int win = 0; win <= 64; win++) {
            if (win < 63 && l < 32)
                idxs[(win + 1) & 1][wv - 2][l] = nums[(win + 1) * 32 + l];
            if (win >= 1) {
                const int pw = win - 1, pwb = pw & 1;
                // L1: relu(b1 + hwin[tk][:128] . W1[:,l]), 16 tokens/thread
                float acc[16];
                #pragma unroll
                for (int i = 0; i < 16; i++) acc[i] = b1o;
                for (int kc = 0; kc < 16; kc++) {
                    v4u wq = *(const v4u*)&W1p[l * 68 + 4 * kc];
                    #pragma unroll
                    for (int i = 0; i < 16; i++) {
                        v4u hq = *(const v4u*)&hwinh[pwb][tb + i][8 * kc];
                        float a = acc[i];
                        a = fdot2f(wq.x, hq.x, a); a = fdot2f(wq.y, hq.y, a);
                        a = fdot2f(wq.z, hq.z, a); a = fdot2f(wq.w, hq.w, a);
                        acc[i] = a;
                    }
                }
                #pragma unroll
                for (int i = 0; i < 16; i++)
                    w1h[(tb + i) * 72 + l] = f2h(fmaxf(acc[i], 0.f));
                // L2: own-wave rows, same-wave LDS ordering (no barrier)
                float a2[8];
                #pragma unroll
                for (int i = 0; i < 8; i++) a2[i] = b2o;
                for (int kc = 0; kc < 8; kc++) {
                    v4u wq = *(const v4u*)&W2p[o2 * 36 + 4 * kc];
                    #pragma unroll
                    for (int i = 0; i < 8; i++) {
                        v4u hq = *(const v4u*)&w1h[(tb + th * 8 + i) * 72 + 8 * kc];
                        float a = a2[i];
                        a = fdot2f(wq.x, hq.x, a); a = fdot2f(wq.y, hq.y, a);
                        a = fdot2f(wq.z, hq.z, a); a = fdot2f(wq.w, hq.w, a);
                        a2[i] = a;
                    }
                }
                #pragma unroll
                for (int i = 0; i < 8; i++)
                    w2buf[(tb + th * 8 + i) * 36 + o2] = fmaxf(a2[i], 0.f);
                // L3: [16 tok][32] @ [32][10]
                if (l < 40) {
                    #pragma unroll
                    for (int i = 0; i < 4; i++) {
                        const int tk = tb + tloc * 4 + i;
                        float a = b3o;
                        #pragma unroll 8
                        for (int k = 0; k < 32; k++)
                            a += W3s[k * 10 + o3] * w2buf[tk * 36 + k];
                        const size_t oi = (size_t)(bb * SEQT + pw * 32 + tk) * NVOCAB + o3;
                        if (outbf) outb[oi] = f2bf(a); else outf[oi] = a;
                    }
                }
            }
            __syncthreads();
        }
    }
}

extern "C" void kernel_launch(void* const* d_in, const int* in_sizes, int n_in,
                              void* d_out, int out_size, void* d_ws, size_t ws_size,
                              hipStream_t stream) {
    const int* num1 = (const int*)d_in[0];
    const int* num2 = (const int*)d_in[1];
    float* ws = (float*)d_ws;

    hipLaunchKernelGGL(init_kernel, dim3(1), dim3(256), 0, stream,
                       d_in[2], d_in[3], d_in[4], d_in[5], d_in[6], d_in[7],
                       d_in[8], d_in[9], d_in[10], d_in[11], ws);
    hipLaunchKernelGGL(lstm_fused, dim3(BSZ), dim3(256), 0, stream,
                       num1, num2, ws, d_out);
}

// Round 6
// 1002.954 us; speedup vs baseline: 2.1187x; 1.0138x over previous
//
#include <hip/hip_runtime.h>
#include <hip/hip_bf16.h>

#define BSZ    256
#define SEQT   2048
#define NVOCAB 10
#define DEMB   32
#define G4     256

typedef unsigned short u16;
typedef unsigned int   u32;
typedef float    v4f __attribute__((ext_vector_type(4)));
typedef u32      v4u __attribute__((ext_vector_type(4)));
typedef _Float16 v2h __attribute__((ext_vector_type(2)));

// ws layout (float slots; some regions hold u32 f16-pair bits)
#define FLAG_OFF 0
#define XZ4_OFF  4                      // [10 v][64 j][4 g] f32 = 2560 (16B aligned)
#define WHP_OFF  (XZ4_OFF + 2560)      // u32 [64 l][4 g][32 kpair] = 8192
#define W1P_OFF  (WHP_OFF + 8192)      // u32 [64 o][64 kpair] = 4096
#define W2P_OFF  (W1P_OFF + 4096)      // u32 [32 o][32 kpair] = 1024
#define W3_OFF   (W2P_OFF + 1024)      // f32 [32][10] = 320
#define B1_OFF   (W3_OFF + 320)
#define B2_OFF   (B1_OFF + 64)
#define B3_OFF   (B2_OFF + 32)

__device__ __forceinline__ float bf2f(u16 x) {
    union { u32 u; float f; } v; v.u = ((u32)x) << 16; return v.f;
}
__device__ __forceinline__ u16 f2bf(float f) {
    union { float f; u32 u; } v; v.f = f;
    u32 r = v.u + 0x7fff + ((v.u >> 16) & 1);
    return (u16)(r >> 16);
}
__device__ __forceinline__ float ldw(const void* p, int i, bool isbf) {
    return isbf ? bf2f(((const u16*)p)[i]) : ((const float*)p)[i];
}
__device__ __forceinline__ float frcp(float x) { return __builtin_amdgcn_rcpf(x); }
__device__ __forceinline__ float sigf(float z) { return frcp(1.f + __expf(-z)); }  // inf-safe
__device__ __forceinline__ u16 f2h(float x) {
    union { _Float16 h; u16 u; } v; v.h = (_Float16)x; return v.u;
}
__device__ __forceinline__ u32 packh2(float lo, float hi) {
    return (u32)f2h(lo) | ((u32)f2h(hi) << 16);
}
__device__ __forceinline__ float fdot2f(u32 a, u32 b, float c) {
    union { u32 u; v2h h; } ua, ub; ua.u = a; ub.u = b;
    return __builtin_amdgcn_fdot2(ua.h, ub.h, c, false);
}
// 4 f16-pair dots: acc += w.h (8 MACs), f32 accumulation
__device__ __forceinline__ void dot4(float& acc, v4u w, v4u h) {
    acc = fdot2f(w.x, h.x, acc); acc = fdot2f(w.y, h.y, acc);
    acc = fdot2f(w.z, h.z, acc); acc = fdot2f(w.w, h.w, acc);
}

// One-time prep: dtype detect, xz float4 table (E@Wx+b: 10 rows), per-lane
// f16-packed Wh table, f16-packed MLP weights.
__global__ void init_kernel(const void* __restrict__ E,  const void* __restrict__ Wx,
                            const void* __restrict__ Wh, const void* __restrict__ bg,
                            const void* __restrict__ W1, const void* __restrict__ b1,
                            const void* __restrict__ W2, const void* __restrict__ b2,
                            const void* __restrict__ W3, const void* __restrict__ b3,
                            float* __restrict__ ws) {
    __shared__ int s_isbf;
    const int tid = threadIdx.x;  // 256 threads, 1 block
    if (tid == 0) s_isbf = 1;
    __syncthreads();
    {   // bf16 data decodes small; fp32 low-halves decode wild exponents
        const u16* Eu = (const u16*)E;
        for (int i = tid; i < NVOCAB * DEMB; i += 256) {
            float v = bf2f(Eu[i]);
            if (!(fabsf(v) < 16.0f)) s_isbf = 0;
        }
    }
    __syncthreads();
    const bool isbf = (s_isbf != 0);
    if (tid == 0) ws[FLAG_OFF] = isbf ? 1.0f : 0.0f;
    u32* wsu = (u32*)ws;

    {   // xz[v][j][g] = b[g*64+j] + sum_d E[v][d]*Wx[d][g*64+j]  (float4 over g)
        const int g = tid >> 6, j = tid & 63, col = g * 64 + j;
        for (int v = 0; v < NVOCAB; v++) {
            float acc = ldw(bg, col, isbf);
            #pragma unroll
            for (int d = 0; d < DEMB; d++)
                acc += ldw(E, v * DEMB + d, isbf) * ldw(Wx, d * G4 + col, isbf);
            ws[XZ4_OFF + (v * 64 + j) * 4 + g] = acc;
        }
    }
    // Wh per-lane table: u32[l*128 + g*32 + kk] = pack(Wh[2kk][g*64+l], Wh[2kk+1][g*64+l])
    for (int i = tid; i < 8192; i += 256) {
        int l = i >> 7, rem = i & 127, g = rem >> 5, kk = rem & 31;
        int col = g * 64 + l;
        wsu[WHP_OFF + i] = packh2(ldw(Wh, (2 * kk) * G4 + col, isbf),
                                  ldw(Wh, (2 * kk + 1) * G4 + col, isbf));
    }
    for (int i = tid; i < 4096; i += 256) {   // W1 [128][64] -> [o][kpair] f16x2
        int o = i >> 6, kk = i & 63;
        wsu[W1P_OFF + i] = packh2(ldw(W1, (2 * kk) * 64 + o, isbf),
                                  ldw(W1, (2 * kk + 1) * 64 + o, isbf));
    }
    for (int i = tid; i < 1024; i += 256) {   // W2 [64][32] -> [o][kpair]
        int o = i >> 5, kk = i & 31;
        wsu[W2P_OFF + i] = packh2(ldw(W2, (2 * kk) * 32 + o, isbf),
                                  ldw(W2, (2 * kk + 1) * 32 + o, isbf));
    }
    for (int i = tid; i < 320; i += 256) ws[W3_OFF + i] = ldw(W3, i, isbf);
    if (tid < 64) ws[B1_OFF + tid] = ldw(b1, tid, isbf);
    if (tid < 32) ws[B2_OFF + tid] = ldw(b2, tid, isbf);
    if (tid < NVOCAB) ws[B3_OFF + tid] = ldw(b3, tid, isbf);
}

// One block (256 thr, 4 waves) per batch element:
//   waves 0,1: one LSTM chain each; Wh register-resident as f16 pairs (128 VGPRs,
//              pinned via empty asm so the allocator cannot spill/rematerialize),
//              v_dot2_f32_f16 matvec, barrier-free steps.
//   waves 2,3: MLP head on the previous 32-token window + index prefetch.
// Block-wide sync once per 32-step window (65 total).
__global__ __launch_bounds__(256, 1) void lstm_fused(
    const int* __restrict__ num1, const int* __restrict__ num2,
    const float* __restrict__ ws, void* __restrict__ outv)
{
    __shared__ __align__(16) float xz4s[2560];          // 10240 B
    __shared__ __align__(16) u16 hwinh[2][32][128];     // 16384 B (f16 h, dbuf window)
    __shared__ __align__(16) u32 W1p[64 * 68];          // 17408 B
    __shared__ __align__(16) u32 W2p[32 * 36];          //  4608 B
    __shared__ float W3s[320];                          //  1280 B
    __shared__ __align__(16) u16 w1h[32 * 72];          //  4608 B
    __shared__ __align__(16) float w2buf[32 * 36];      //  4608 B
    __shared__ int idxs[2][2][32];                      //   512 B  -> ~59.6 KB

    const int tid = threadIdx.x, bb = blockIdx.x;
    const int wv = tid >> 6, l = tid & 63;
    const u32* wsu = (const u32*)ws;
    const bool outbf = (ws[FLAG_OFF] != 0.0f);

    for (int i = tid; i < 2560; i += 256) xz4s[i] = ws[XZ4_OFF + i];
    for (int i = tid; i < 4096; i += 256) { int o = i >> 6, kk = i & 63; W1p[o * 68 + kk] = wsu[W1P_OFF + i]; }
    for (int i = tid; i < 1024; i += 256) { int o = i >> 5, kk = i & 31; W2p[o * 36 + kk] = wsu[W2P_OFF + i]; }
    for (int i = tid; i < 320; i += 256) W3s[i] = ws[W3_OFF + i];
    if (tid < 128) hwinh[1][31][tid] = 0;               // h_{-1} = 0 (f16 zero)
    if (tid < 64) { int c0 = tid >> 5, tt = tid & 31;
                    idxs[0][c0][tt] = (c0 == 0 ? num1 : num2)[bb * SEQT + tt]; }

    if (wv < 2) {
        // -------- recurrence wave: chain wv, lane l = unit --------
        v4u whq[32];                                    // 128 VGPRs of f16-pair Wh
        {
            const v4u* whsrc = (const v4u*)(wsu + WHP_OFF) + (size_t)l * 32;
            #pragma unroll
            for (int i = 0; i < 32; i++) whq[i] = whsrc[i];
        }
        // PIN: force each quad into VGPRs and make it opaque — the allocator
        // can no longer re-load from global or park it in AGPRs behind copies.
        #pragma unroll
        for (int i = 0; i < 32; i++) asm volatile("" : "+v"(whq[i]));
        float c = 0.f;
        __syncthreads();
        for (int win = 0; win <= 64; win++) {
            if (win < 64) {
                const int wb = win & 1;
                #pragma unroll 1
                for (int tt = 0; tt < 32; tt++) {
                    const int idx  = idxs[wb][wv][tt];
                    const int rbuf = (tt == 0) ? 1 - wb : wb;
                    const int rrow = (tt + 31) & 31;
                    const v4u* hp = (const v4u*)&hwinh[rbuf][rrow][wv * 64];
                    v4u hh[8];
                    #pragma unroll
                    for (int q = 0; q < 8; q++) hh[q] = hp[q];
                    v4f xzv = *(const v4f*)&xz4s[(idx * 64 + l) * 4];
                    float ai0 = 0.f, af0 = 0.f, ag0 = 0.f, ao0 = 0.f;
                    float ai1 = 0.f, af1 = 0.f, ag1 = 0.f, ao1 = 0.f;
                    #pragma unroll
                    for (int q = 0; q < 4; q++) {
                        dot4(ai0, whq[q],      hh[q]);
                        dot4(af0, whq[8 + q],  hh[q]);
                        dot4(ag0, whq[16 + q], hh[q]);
                        dot4(ao0, whq[24 + q], hh[q]);
                    }
                    #pragma unroll
                    for (int q = 4; q < 8; q++) {
                        dot4(ai1, whq[q],      hh[q]);
                        dot4(af1, whq[8 + q],  hh[q]);
                        dot4(ag1, whq[16 + q], hh[q]);
                        dot4(ao1, whq[24 + q], hh[q]);
                    }
                    float zi = ai0 + ai1 + xzv.x, zf = af0 + af1 + xzv.y;
                    float zg = ag0 + ag1 + xzv.z, zo = ao0 + ao1 + xzv.w;
                    float gi = sigf(zi), gf = sigf(zf);
                    float gG = 2.f * sigf(2.f * zg) - 1.f, go = sigf(zo);
                    c = gf * c + gi * gG;
                    float th = 1.f - 2.f * frcp(__expf(2.f * c) + 1.f);  // inf-safe tanh
                    hwinh[wb][tt][wv * 64 + l] = f2h(go * th);
                    // same-wave DS ordering: next step's read needs no barrier
                }
            }
            __syncthreads();
        }
    } else {
        // -------- MLP wave: tokens [tb, tb+16) of previous window --------
        const int tb = (wv - 2) * 16;
        const float b1o = ws[B1_OFF + l];
        const int th = l >> 5, o2 = l & 31;
        const float b2o = ws[B2_OFF + o2];
        const int tloc = l / 10, o3 = l - tloc * 10;
        const float b3o = (l < 40) ? ws[B3_OFF + o3] : 0.f;
        const int* nums = (wv == 2 ? num1 : num2) + bb * SEQT;
        u16* outb = (u16*)outv; float* outf = (float*)outv;
        __syncthreads();
        // hoist W3 column into registers (loop-invariant; kills 256 ds_read_b32/window)
        float w3r[32];
        #pragma unroll
        for (int k = 0; k < 32; k++) w3r[k] = (l < 40) ? W3s[k * 10 + o3] : 0.f;
        for (int win = 0; win <= 64; win++) {
            if (win < 63 && l < 32)
                idxs[(win + 1) & 1][wv - 2][l] = nums[(win + 1) * 32 + l];
            if (win >= 1) {
                const int pw = win - 1, pwb = pw & 1;
                // L1: relu(b1 + hwin[tk][:128] . W1[:,l]), 16 tokens/thread
                float acc[16];
                #pragma unroll
                for (int i = 0; i < 16; i++) acc[i] = b1o;
                for (int kc = 0; kc < 16; kc++) {
                    v4u wq = *(const v4u*)&W1p[l * 68 + 4 * kc];
                    #pragma unroll
                    for (int i = 0; i < 16; i++) {
                        v4u hq = *(const v4u*)&hwinh[pwb][tb + i][8 * kc];
                        float a = acc[i];
                        a = fdot2f(wq.x, hq.x, a); a = fdot2f(wq.y, hq.y, a);
                        a = fdot2f(wq.z, hq.z, a); a = fdot2f(wq.w, hq.w, a);
                        acc[i] = a;
                    }
                }
                #pragma unroll
                for (int i = 0; i < 16; i++)
                    w1h[(tb + i) * 72 + l] = f2h(fmaxf(acc[i], 0.f));
                // L2: own-wave rows, same-wave LDS ordering (no barrier)
                float a2[8];
                #pragma unroll
                for (int i = 0; i < 8; i++) a2[i] = b2o;
                for (int kc = 0; kc < 8; kc++) {
                    v4u wq = *(const v4u*)&W2p[o2 * 36 + 4 * kc];
                    #pragma unroll
                    for (int i = 0; i < 8; i++) {
                        v4u hq = *(const v4u*)&w1h[(tb + th * 8 + i) * 72 + 8 * kc];
                        float a = a2[i];
                        a = fdot2f(wq.x, hq.x, a); a = fdot2f(wq.y, hq.y, a);
                        a = fdot2f(wq.z, hq.z, a); a = fdot2f(wq.w, hq.w, a);
                        a2[i] = a;
                    }
                }
                #pragma unroll
                for (int i = 0; i < 8; i++)
                    w2buf[(tb + th * 8 + i) * 36 + o2] = fmaxf(a2[i], 0.f);
                // L3: [16 tok][32] @ [32][10], vectorized w2 reads, W3 in regs
                if (l < 40) {
                    #pragma unroll
                    for (int i = 0; i < 4; i++) {
                        const int tk = tb + tloc * 4 + i;
                        const v4f* wp = (const v4f*)&w2buf[tk * 36];
                        float a = b3o;
                        #pragma unroll
                        for (int q = 0; q < 8; q++) {
                            v4f w4 = wp[q];
                            a += w3r[4 * q]     * w4.x + w3r[4 * q + 1] * w4.y
                               + w3r[4 * q + 2] * w4.z + w3r[4 * q + 3] * w4.w;
                        }
                        const size_t oi = (size_t)(bb * SEQT + pw * 32 + tk) * NVOCAB + o3;
                        if (outbf) outb[oi] = f2bf(a); else outf[oi] = a;
                    }
                }
            }
            __syncthreads();
        }
    }
}

extern "C" void kernel_launch(void* const* d_in, const int* in_sizes, int n_in,
                              void* d_out, int out_size, void* d_ws, size_t ws_size,
                              hipStream_t stream) {
    const int* num1 = (const int*)d_in[0];
    const int* num2 = (const int*)d_in[1];
    float* ws = (float*)d_ws;

    hipLaunchKernelGGL(init_kernel, dim3(1), dim3(256), 0, stream,
                       d_in[2], d_in[3], d_in[4], d_in[5], d_in[6], d_in[7],
                       d_in[8], d_in[9], d_in[10], d_in[11], ws);
    hipLaunchKernelGGL(lstm_fused, dim3(BSZ), dim3(256), 0, stream,
                       num1, num2, ws, d_out);
}

// Round 8
// 980.656 us; speedup vs baseline: 2.1669x; 1.0227x over previous
//
#include <hip/hip_runtime.h>
#include <hip/hip_bf16.h>

#define BSZ    256
#define SEQT   2048
#define NVOCAB 10
#define DEMB   32
#define G4     256
#define BLK    384   // 6 waves: 0,1 = recurrence; 2..5 = MLP (SIMD co-residency)

typedef unsigned short u16;
typedef unsigned int   u32;
typedef float    v4f __attribute__((ext_vector_type(4)));
typedef u32      v4u __attribute__((ext_vector_type(4)));
typedef _Float16 v2h __attribute__((ext_vector_type(2)));

// ws layout (float slots; some regions hold u32 f16-pair bits)
#define FLAG_OFF 0
#define XZ4_OFF  4                      // [10 v][64 j][4 g] f32 = 2560 (16B aligned)
#define WHP_OFF  (XZ4_OFF + 2560)      // u32 [64 l][4 g][32 kpair] = 8192
#define W1P_OFF  (WHP_OFF + 8192)      // u32 [64 o][64 kpair] = 4096
#define W2P_OFF  (W1P_OFF + 4096)      // u32 [32 o][32 kpair] = 1024
#define W3_OFF   (W2P_OFF + 1024)      // f32 [32][10] = 320
#define B1_OFF   (W3_OFF + 320)
#define B2_OFF   (B1_OFF + 64)
#define B3_OFF   (B2_OFF + 32)

__device__ __forceinline__ float bf2f(u16 x) {
    union { u32 u; float f; } v; v.u = ((u32)x) << 16; return v.f;
}
__device__ __forceinline__ u16 f2bf(float f) {
    union { float f; u32 u; } v; v.f = f;
    u32 r = v.u + 0x7fff + ((v.u >> 16) & 1);
    return (u16)(r >> 16);
}
__device__ __forceinline__ float ldw(const void* p, int i, bool isbf) {
    return isbf ? bf2f(((const u16*)p)[i]) : ((const float*)p)[i];
}
__device__ __forceinline__ float frcp(float x) { return __builtin_amdgcn_rcpf(x); }
__device__ __forceinline__ float sigf(float z) { return frcp(1.f + __expf(-z)); }  // inf-safe
__device__ __forceinline__ u16 f2h(float x) {
    union { _Float16 h; u16 u; } v; v.h = (_Float16)x; return v.u;
}
__device__ __forceinline__ u32 packh2(float lo, float hi) {
    return (u32)f2h(lo) | ((u32)f2h(hi) << 16);
}
__device__ __forceinline__ float fdot2f(u32 a, u32 b, float c) {
    union { u32 u; v2h h; } ua, ub; ua.u = a; ub.u = b;
    return __builtin_amdgcn_fdot2(ua.h, ub.h, c, false);
}
// 4 f16-pair dots: acc += w.h (8 MACs), f32 accumulation
__device__ __forceinline__ void dot4(float& acc, v4u w, v4u h) {
    acc = fdot2f(w.x, h.x, acc); acc = fdot2f(w.y, h.y, acc);
    acc = fdot2f(w.z, h.z, acc); acc = fdot2f(w.w, h.w, acc);
}

// One-time prep: dtype detect, xz float4 table (E@Wx+b: 10 rows), per-lane
// f16-packed Wh table, f16-packed MLP weights.
__global__ void init_kernel(const void* __restrict__ E,  const void* __restrict__ Wx,
                            const void* __restrict__ Wh, const void* __restrict__ bg,
                            const void* __restrict__ W1, const void* __restrict__ b1,
                            const void* __restrict__ W2, const void* __restrict__ b2,
                            const void* __restrict__ W3, const void* __restrict__ b3,
                            float* __restrict__ ws) {
    __shared__ int s_isbf;
    const int tid = threadIdx.x;  // 256 threads, 1 block
    if (tid == 0) s_isbf = 1;
    __syncthreads();
    {   // bf16 data decodes small; fp32 low-halves decode wild exponents
        const u16* Eu = (const u16*)E;
        for (int i = tid; i < NVOCAB * DEMB; i += 256) {
            float v = bf2f(Eu[i]);
            if (!(fabsf(v) < 16.0f)) s_isbf = 0;
        }
    }
    __syncthreads();
    const bool isbf = (s_isbf != 0);
    if (tid == 0) ws[FLAG_OFF] = isbf ? 1.0f : 0.0f;
    u32* wsu = (u32*)ws;

    {   // xz[v][j][g] = b[g*64+j] + sum_d E[v][d]*Wx[d][g*64+j]  (float4 over g)
        const int g = tid >> 6, j = tid & 63, col = g * 64 + j;
        for (int v = 0; v < NVOCAB; v++) {
            float acc = ldw(bg, col, isbf);
            #pragma unroll
            for (int d = 0; d < DEMB; d++)
                acc += ldw(E, v * DEMB + d, isbf) * ldw(Wx, d * G4 + col, isbf);
            ws[XZ4_OFF + (v * 64 + j) * 4 + g] = acc;
        }
    }
    // Wh per-lane table: u32[l*128 + g*32 + kk] = pack(Wh[2kk][g*64+l], Wh[2kk+1][g*64+l])
    for (int i = tid; i < 8192; i += 256) {
        int l = i >> 7, rem = i & 127, g = rem >> 5, kk = rem & 31;
        int col = g * 64 + l;
        wsu[WHP_OFF + i] = packh2(ldw(Wh, (2 * kk) * G4 + col, isbf),
                                  ldw(Wh, (2 * kk + 1) * G4 + col, isbf));
    }
    for (int i = tid; i < 4096; i += 256) {   // W1 [128][64] -> [o][kpair] f16x2
        int o = i >> 6, kk = i & 63;
        wsu[W1P_OFF + i] = packh2(ldw(W1, (2 * kk) * 64 + o, isbf),
                                  ldw(W1, (2 * kk + 1) * 64 + o, isbf));
    }
    for (int i = tid; i < 1024; i += 256) {   // W2 [64][32] -> [o][kpair]
        int o = i >> 5, kk = i & 31;
        wsu[W2P_OFF + i] = packh2(ldw(W2, (2 * kk) * 32 + o, isbf),
                                  ldw(W2, (2 * kk + 1) * 32 + o, isbf));
    }
    for (int i = tid; i < 320; i += 256) ws[W3_OFF + i] = ldw(W3, i, isbf);
    if (tid < 64) ws[B1_OFF + tid] = ldw(b1, tid, isbf);
    if (tid < 32) ws[B2_OFF + tid] = ldw(b2, tid, isbf);
    if (tid < NVOCAB) ws[B3_OFF + tid] = ldw(b3, tid, isbf);
}

// One block (384 thr, 6 waves) per batch element. Wave->SIMD is round-robin:
//   SIMD0: wave0 (rec chain0) + wave4 (MLP)   <- MLP fills rec stall gaps
//   SIMD1: wave1 (rec chain1) + wave5 (MLP)
//   SIMD2: wave2 (MLP), SIMD3: wave3 (MLP)
// Recurrence waves: Wh register-resident as f16 pairs, pinned INSIDE the loop;
// barrier-free steps (same-wave DS ordering). One block barrier per 32-step window.
__global__ __launch_bounds__(BLK, 2) void lstm_fused(
    const int* __restrict__ num1, const int* __restrict__ num2,
    const float* __restrict__ ws, void* __restrict__ outv)
{
    __shared__ __align__(16) float xz4s[2560];          // 10240 B
    __shared__ __align__(16) u16 hwinh[2][32][128];     // 16384 B (f16 h, dbuf window)
    __shared__ __align__(16) u32 W1p[64 * 68];          // 17408 B
    __shared__ __align__(16) u32 W2p[32 * 36];          //  4608 B
    __shared__ float W3s[320];                          //  1280 B
    __shared__ __align__(16) u16 w1h[32 * 72];          //  4608 B
    __shared__ __align__(16) float w2buf[32 * 36];      //  4608 B
    __shared__ int idxs[2][2][32];                      //   512 B  -> ~59.6 KB

    const int tid = threadIdx.x, bb = blockIdx.x;
    const int wv = tid >> 6, l = tid & 63;
    const u32* wsu = (const u32*)ws;
    const bool outbf = (ws[FLAG_OFF] != 0.0f);

    for (int i = tid; i < 2560; i += BLK) xz4s[i] = ws[XZ4_OFF + i];
    for (int i = tid; i < 4096; i += BLK) { int o = i >> 6, kk = i & 63; W1p[o * 68 + kk] = wsu[W1P_OFF + i]; }
    for (int i = tid; i < 1024; i += BLK) { int o = i >> 5, kk = i & 31; W2p[o * 36 + kk] = wsu[W2P_OFF + i]; }
    for (int i = tid; i < 320; i += BLK) W3s[i] = ws[W3_OFF + i];
    if (tid < 128) hwinh[1][31][tid] = 0;               // h_{-1} = 0 (f16 zero)
    if (tid < 64) { int c0 = tid >> 5, tt = tid & 31;
                    idxs[0][c0][tt] = (c0 == 0 ? num1 : num2)[bb * SEQT + tt]; }

    if (wv < 2) {
        // -------- recurrence wave: chain wv, lane l = unit --------
        v4u whq[32];                                    // 128 VGPRs of f16-pair Wh
        {
            const v4u* whsrc = (const v4u*)(wsu + WHP_OFF) + (size_t)l * 32;
            #pragma unroll
            for (int i = 0; i < 32; i++) whq[i] = whsrc[i];
        }
        float c = 0.f;
        __syncthreads();
        for (int win = 0; win <= 64; win++) {
            // PIN inside the loop: whq must be live in VGPRs across the
            // back-edge -> allocator cannot sink the loads into the loop.
            #pragma unroll
            for (int i = 0; i < 32; i++) asm("" : "+v"(whq[i]));
            if (win < 64) {
                const int wb = win & 1;
                #pragma unroll 1
                for (int tt = 0; tt < 32; tt++) {
                    const int idx  = idxs[wb][wv][tt];
                    const int rbuf = (tt == 0) ? 1 - wb : wb;
                    const int rrow = (tt + 31) & 31;
                    const v4u* hp = (const v4u*)&hwinh[rbuf][rrow][wv * 64];
                    v4u hh[8];
                    #pragma unroll
                    for (int q = 0; q < 8; q++) hh[q] = hp[q];
                    v4f xzv = *(const v4f*)&xz4s[(idx * 64 + l) * 4];
                    float ai0 = 0.f, af0 = 0.f, ag0 = 0.f, ao0 = 0.f;
                    float ai1 = 0.f, af1 = 0.f, ag1 = 0.f, ao1 = 0.f;
                    #pragma unroll
                    for (int q = 0; q < 4; q++) {
                        dot4(ai0, whq[q],      hh[q]);
                        dot4(af0, whq[8 + q],  hh[q]);
                        dot4(ag0, whq[16 + q], hh[q]);
                        dot4(ao0, whq[24 + q], hh[q]);
                    }
                    #pragma unroll
                    for (int q = 4; q < 8; q++) {
                        dot4(ai1, whq[q],      hh[q]);
                        dot4(af1, whq[8 + q],  hh[q]);
                        dot4(ag1, whq[16 + q], hh[q]);
                        dot4(ao1, whq[24 + q], hh[q]);
                    }
                    float zi = ai0 + ai1 + xzv.x, zf = af0 + af1 + xzv.y;
                    float zg = ag0 + ag1 + xzv.z, zo = ao0 + ao1 + xzv.w;
                    float gi = sigf(zi), gf = sigf(zf);
                    float gG = 2.f * sigf(2.f * zg) - 1.f, go = sigf(zo);
                    c = gf * c + gi * gG;
                    float th = 1.f - 2.f * frcp(__expf(2.f * c) + 1.f);  // inf-safe tanh
                    hwinh[wb][tt][wv * 64 + l] = f2h(go * th);
                    // same-wave DS ordering: next step's read needs no barrier
                }
            }
            __syncthreads();
        }
    } else {
        // -------- MLP wave mw = wv-2: tokens [8*mw, 8*mw+8) of previous window ----
        const int mw = wv - 2;
        const int tb = mw * 8;
        const float b1o = ws[B1_OFF + l];
        const int th = l >> 5, o2 = l & 31;
        const float b2o = ws[B2_OFF + o2];
        const int tloc = l / 10, o3 = l - tloc * 10;
        const float b3o = (l < 40) ? ws[B3_OFF + o3] : 0.f;
        u16* outb = (u16*)outv; float* outf = (float*)outv;
        __syncthreads();
        // hoist W3 column into registers (loop-invariant)
        float w3r[32];
        #pragma unroll
        for (int k = 0; k < 32; k++) w3r[k] = (l < 40) ? W3s[k * 10 + o3] : 0.f;
        for (int win = 0; win <= 64; win++) {
            if (win < 63 && mw < 2 && l < 32)   // waves 2,3 prefetch next idx window
                idxs[(win + 1) & 1][mw][l] =
                    (mw == 0 ? num1 : num2)[bb * SEQT + (win + 1) * 32 + l];
            if (win >= 1) {
                const int pw = win - 1, pwb = pw & 1;
                // L1: relu(b1 + hwin[tk][:128] . W1[:,l]), 8 tokens/wave
                float acc[8];
                #pragma unroll
                for (int i = 0; i < 8; i++) acc[i] = b1o;
                for (int kc = 0; kc < 16; kc++) {
                    v4u wq = *(const v4u*)&W1p[l * 68 + 4 * kc];
                    #pragma unroll
                    for (int i = 0; i < 8; i++) {
                        v4u hq = *(const v4u*)&hwinh[pwb][tb + i][8 * kc];
                        float a = acc[i];
                        a = fdot2f(wq.x, hq.x, a); a = fdot2f(wq.y, hq.y, a);
                        a = fdot2f(wq.z, hq.z, a); a = fdot2f(wq.w, hq.w, a);
                        acc[i] = a;
                    }
                }
                #pragma unroll
                for (int i = 0; i < 8; i++)
                    w1h[(tb + i) * 72 + l] = f2h(fmaxf(acc[i], 0.f));
                // L2: own-wave rows, same-wave LDS ordering (no barrier)
                float a2[4];
                #pragma unroll
                for (int i = 0; i < 4; i++) a2[i] = b2o;
                for (int kc = 0; kc < 8; kc++) {
                    v4u wq = *(const v4u*)&W2p[o2 * 36 + 4 * kc];
                    #pragma unroll
                    for (int i = 0; i < 4; i++) {
                        v4u hq = *(const v4u*)&w1h[(tb + th * 4 + i) * 72 + 8 * kc];
                        float a = a2[i];
                        a = fdot2f(wq.x, hq.x, a); a = fdot2f(wq.y, hq.y, a);
                        a = fdot2f(wq.z, hq.z, a); a = fdot2f(wq.w, hq.w, a);
                        a2[i] = a;
                    }
                }
                #pragma unroll
                for (int i = 0; i < 4; i++)
                    w2buf[(tb + th * 4 + i) * 36 + o2] = fmaxf(a2[i], 0.f);
                // L3: 8 tokens @ [32][10], vectorized w2 reads, W3 in regs
                if (l < 40) {
                    #pragma unroll
                    for (int i = 0; i < 2; i++) {
                        const int tk = tb + tloc * 2 + i;
                        const v4f* wp = (const v4f*)&w2buf[tk * 36];
                        float a = b3o;
                        #pragma unroll
                        for (int q = 0; q < 8; q++) {
                            v4f w4 = wp[q];
                            a += w3r[4 * q]     * w4.x + w3r[4 * q + 1] * w4.y
                               + w3r[4 * q + 2] * w4.z + w3r[4 * q + 3] * w4.w;
                        }
                        const size_t oi = (size_t)(bb * SEQT + pw * 32 + tk) * NVOCAB + o3;
                        if (outbf) outb[oi] = f2bf(a); else outf[oi] = a;
                    }
                }
            }
            __syncthreads();
        }
    }
}

extern "C" void kernel_launch(void* const* d_in, const int* in_sizes, int n_in,
                              void* d_out, int out_size, void* d_ws, size_t ws_size,
                              hipStream_t stream) {
    const int* num1 = (const int*)d_in[0];
    const int* num2 = (const int*)d_in[1];
    float* ws = (float*)d_ws;

    hipLaunchKernelGGL(init_kernel, dim3(1), dim3(256), 0, stream,
                       d_in[2], d_in[3], d_in[4], d_in[5], d_in[6], d_in[7],
                       d_in[8], d_in[9], d_in[10], d_in[11], ws);
    hipLaunchKernelGGL(lstm_fused, dim3(BSZ), dim3(BLK), 0, stream,
                       num1, num2, ws, d_out);
}